// Round 7
// baseline (82.203 us; speedup 1.0000x reference)
//
#include <hip/hip_runtime.h>
#include <math.h>
#include <stdint.h>

// Problem constants
#define NCH   8
#define DNX   128
#define DNY   128
#define KPTS  16384

typedef __attribute__((ext_vector_type(8))) short bf16x8;   // MFMA A/B frag (8 bf16)
typedef __attribute__((ext_vector_type(4))) float f32x4;    // MFMA C/D frag

// fp32 -> bf16 bits, round-to-nearest-even
__device__ __forceinline__ unsigned short f2bf(float f) {
    union { float f; uint32_t u; } v; v.f = f;
    uint32_t r = (v.u + 0x7fffu + ((v.u >> 16) & 1u)) >> 16;
    return (unsigned short)r;
}

// Sum over each 16-lane row via DPP (pure VALU — keeps LDS pipe free).
__device__ __forceinline__ float dpp_sum16(float v) {
    v += __int_as_float(__builtin_amdgcn_update_dpp(0, __float_as_int(v), 0xB1,  0xF, 0xF, true));
    v += __int_as_float(__builtin_amdgcn_update_dpp(0, __float_as_int(v), 0x4E,  0xF, 0xF, true));
    v += __int_as_float(__builtin_amdgcn_update_dpp(0, __float_as_int(v), 0x141, 0xF, 0xF, true));
    v += __int_as_float(__builtin_amdgcn_update_dpp(0, __float_as_int(v), 0x140, 0xF, 0xF, true));
    return v;
}

// ---------------------------------------------------------------------------
// Single fused kernel: block = 4 waves, each wave owns 32 k (2 k-groups).
// Grid (128 kblocks, 4 chan-groups of 2 channels). No workspace.
// Per channel: fused staging (fp32 img -> bf16 swizzled LDS, prep's verified
// mapping), then MFMA stage 1 + lane-local rotor stage 2 + DPP reduce.
// LDS B layout: logical B[x][col], col = 2y+s; addr =
// (256*col + 64*t4 + 16*q) ^ (16*(col&7)) + 2*j, x = 32*t4 + 8*q + j.
// ---------------------------------------------------------------------------
__global__ __launch_bounds__(256, 2) void nudft_mfma_kernel(
    const float* __restrict__ img_real,
    const float* __restrict__ img_imag,
    const float* __restrict__ trj,
    float* __restrict__ out)
{
    __shared__ __align__(16) unsigned short Bl[32768];   // 64 KB single buffer

    const int t    = threadIdx.x;
    const int lane = t & 63;
    const int m    = lane & 15;       // MFMA row (A) / col (C) index
    const int quad = (lane >> 4) & 3;
    const int spar = m & 1;           // col parity: 0 = re-col, 1 = im-col
    const int kb   = blockIdx.x;      // 0..127
    const int cg   = blockIdx.y;      // 0..3 -> channels 2cg, 2cg+1
    const int k0w  = kb * 128 + (t >> 6) * 32;

    // ---- A fragments (px) via incremental rotation:
    // A[m][x = 32*t4 + 8*quad + j]; theta(x) = d1*(x-64) pi-units, d1 = -trjx/64
    bf16x8 pxr[2][4], pxi[2][4];
    #pragma unroll
    for (int kg = 0; kg < 2; ++kg) {
        const float trjx = trj[2 * (k0w + kg * 16 + m) + 0];
        const float d1 = -trjx * (1.0f / 64.0f);
        float s1, c1;  sincospif(d1, &s1, &c1);            // rot per +1 x
        float s32, c32; sincospif(d1 * 32.0f, &s32, &c32); // rot per +32 x (t4 step)
        float ps, pc;  sincospif(d1 * (float)(8 * quad - 64), &ps, &pc);
        #pragma unroll
        for (int t4 = 0; t4 < 4; ++t4) {
            float qc = pc, qs = ps;
            #pragma unroll
            for (int j = 0; j < 8; ++j) {
                pxr[kg][t4][j] = (short)f2bf(qc);
                pxi[kg][t4][j] = (short)f2bf(qs);
                if (j < 7) {
                    float tq = qc * c1 - qs * s1;
                    qs = fmaf(qc, s1, qs * c1);
                    qc = tq;
                }
            }
            if (t4 < 3) {
                float tp = pc * c32 - ps * s32;
                ps = fmaf(pc, s32, ps * c32);
                pc = tp;
            }
        }
    }

    // ---- stage-2 rotor init. Lane element idx=(kg,r): k = k0w+kg*16+quad*4+r,
    // y = ct*8 + ybase, ybase = m>>1. (cb,sb) = cos/sin(pi * -ty*(y-64)/64);
    // per-ct step rotor (dr,di) = cos/sin(pi * -ty/8). Parity-independent.
    const int ybase = m >> 1;
    float cb0[8], sb0[8], dr[8], di[8];
    #pragma unroll
    for (int kg = 0; kg < 2; ++kg) {
        #pragma unroll
        for (int r = 0; r < 4; ++r) {
            int idx = kg * 4 + r;
            float ty = trj[2 * (k0w + kg * 16 + quad * 4 + r) + 1];
            float sb, cbv; sincospif(-ty * (float)(ybase - 64) * (1.0f / 64.0f), &sb, &cbv);
            cb0[idx] = cbv; sb0[idx] = sb;
            float sd, cd; sincospif(-ty * 0.125f, &sd, &cd);
            dr[idx] = cd; di[idx] = sd;
        }
    }

    const int A0 = 256 * m + 16 * quad;
    const int Mx = 16 * (m & 7);             // XOR swizzle mask (col&7 == m&7)

    // staging identity: thread t covers slots u = t + 256*it ->
    // y = t&127 (fixed), v = (t>>7) + 2*it in [0,32): xc = v&15, s = v>>4.
    const int yst = t & 127;
    const int bst = t >> 7;

    #pragma unroll 1
    for (int cc = 0; cc < 2; ++cc) {
        const int c = cg * 2 + cc;

        __syncthreads();   // previous channel fully consumed

        // ---- fused prep: stage channel c from fp32 planes into swizzled LDS
        {
            const float* rep = img_real + c * (DNX * DNY) + yst;
            const float* imp = img_imag + c * (DNX * DNY) + yst;
            #pragma unroll 4
            for (int it = 0; it < 16; ++it) {
                int v  = bst + 2 * it;
                int xc = v & 15;
                int s  = v >> 4;
                int t4 = xc >> 2, q = xc & 3;
                int x0 = 32 * t4 + 8 * q;
                const float* src = s ? imp : rep;
                unsigned short pk[8];
                #pragma unroll
                for (int j = 0; j < 8; ++j) pk[j] = f2bf(src[(x0 + j) * DNY]);
                int col  = 2 * yst + s;
                int dest = (256 * col + 64 * t4 + 16 * q) ^ (16 * (col & 7));
                uint4 val;
                val.x = (uint32_t)pk[0] | ((uint32_t)pk[1] << 16);
                val.y = (uint32_t)pk[2] | ((uint32_t)pk[3] << 16);
                val.z = (uint32_t)pk[4] | ((uint32_t)pk[5] << 16);
                val.w = (uint32_t)pk[6] | ((uint32_t)pk[7] << 16);
                *(uint4*)((char*)&Bl[0] + dest) = val;
            }
        }
        __syncthreads();   // staging complete

        float F[8], G[8], cb[8], sb[8];
        #pragma unroll
        for (int idx = 0; idx < 8; ++idx) {
            F[idx] = 0.f; G[idx] = 0.f;
            cb[idx] = cb0[idx]; sb[idx] = sb0[idx];
        }

        #pragma unroll 2
        for (int ct = 0; ct < 16; ++ct) {
            f32x4 acc1[2], acc2[2];
            #pragma unroll
            for (int kg = 0; kg < 2; ++kg) {
                acc1[kg] = (f32x4){0.f, 0.f, 0.f, 0.f};
                acc2[kg] = (f32x4){0.f, 0.f, 0.f, 0.f};
            }
            const int Act = A0 + 4096 * ct;
            #pragma unroll
            for (int t4 = 0; t4 < 4; ++t4) {
                int addr = (Act + 64 * t4) ^ Mx;
                bf16x8 bfrag = *(const bf16x8*)((const char*)&Bl[0] + addr);
                acc1[0] = __builtin_amdgcn_mfma_f32_16x16x32_bf16(pxr[0][t4], bfrag, acc1[0], 0, 0, 0);
                acc2[0] = __builtin_amdgcn_mfma_f32_16x16x32_bf16(pxi[0][t4], bfrag, acc2[0], 0, 0, 0);
                acc1[1] = __builtin_amdgcn_mfma_f32_16x16x32_bf16(pxr[1][t4], bfrag, acc1[1], 0, 0, 0);
                acc2[1] = __builtin_amdgcn_mfma_f32_16x16x32_bf16(pxi[1][t4], bfrag, acc2[1], 0, 0, 0);
            }
            #pragma unroll
            for (int kg = 0; kg < 2; ++kg) {
                #pragma unroll
                for (int r = 0; r < 4; ++r) {
                    const int idx = kg * 4 + r;
                    float a1 = acc1[kg][r], a2 = acc2[kg][r];
                    F[idx] = fmaf(a1, cb[idx], F[idx]);
                    F[idx] = fmaf(-a2, sb[idx], F[idx]);
                    G[idx] = fmaf(a1, sb[idx], G[idx]);
                    G[idx] = fmaf(a2, cb[idx], G[idx]);
                    // advance rotor
                    float tz = cb[idx] * dr[idx] - sb[idx] * di[idx];
                    sb[idx]  = fmaf(cb[idx], di[idx], sb[idx] * dr[idx]);
                    cb[idx]  = tz;
                }
            }
        }

        // per-lane parity assignment, then 16-lane DPP reduction (VALU only)
        #pragma unroll
        for (int idx = 0; idx < 8; ++idx) {
            float kre_p = spar ? -G[idx] : F[idx];
            float kim_p = spar ?  F[idx] : G[idx];
            float kre_s = dpp_sum16(kre_p);
            float kim_s = dpp_sum16(kim_p);
            if (m == 0) {
                int kg = idx >> 2, r = idx & 3;
                int k = k0w + kg * 16 + quad * 4 + r;
                out[(size_t)c * KPTS + k]                      = kre_s;
                out[(size_t)NCH * KPTS + (size_t)c * KPTS + k] = kim_s;
            }
        }
    }
}

extern "C" void kernel_launch(void* const* d_in, const int* in_sizes, int n_in,
                              void* d_out, int out_size, void* d_ws, size_t ws_size,
                              hipStream_t stream)
{
    const float* img_real = (const float*)d_in[0];  // (8,128,128) fp32
    const float* img_imag = (const float*)d_in[1];  // (8,128,128) fp32
    const float* trj      = (const float*)d_in[2];  // (16384,2) fp32
    float* out = (float*)d_out;                      // planar: re block then im block
    (void)d_ws; (void)ws_size;                       // workspace intentionally unused

    nudft_mfma_kernel<<<dim3(128, 4), 256, 0, stream>>>(img_real, img_imag, trj, out);
}

// Round 8
// 79.701 us; speedup vs baseline: 1.0314x; 1.0314x over previous
//
#include <hip/hip_runtime.h>
#include <hip/hip_bf16.h>
#include <math.h>
#include <stdint.h>

// Problem constants
#define NCH   8
#define DNX   128
#define DNY   128
#define KPTS  16384

typedef __attribute__((ext_vector_type(8))) short bf16x8;   // MFMA A/B frag (8 bf16)
typedef __attribute__((ext_vector_type(4))) float f32x4;    // MFMA C/D frag

typedef const __attribute__((address_space(1))) unsigned int* gp_t;
typedef __attribute__((address_space(3))) unsigned int* lp_t;

// pack two fp32 -> one uint32 of two bf16 (RNE) via v_cvt_pk_bf16_f32
__device__ __forceinline__ uint32_t pkbf(float lo, float hi) {
    union { __hip_bfloat162 h; uint32_t u; } v;
    v.h = __float22bfloat162_rn(make_float2(lo, hi));
    return v.u;
}

// Sum over each 16-lane row via DPP (pure VALU — keeps LDS pipe free).
__device__ __forceinline__ float dpp_sum16(float v) {
    v += __int_as_float(__builtin_amdgcn_update_dpp(0, __float_as_int(v), 0xB1,  0xF, 0xF, true));
    v += __int_as_float(__builtin_amdgcn_update_dpp(0, __float_as_int(v), 0x4E,  0xF, 0xF, true));
    v += __int_as_float(__builtin_amdgcn_update_dpp(0, __float_as_int(v), 0x141, 0xF, 0xF, true));
    v += __int_as_float(__builtin_amdgcn_update_dpp(0, __float_as_int(v), 0x140, 0xF, 0xF, true));
    return v;
}

// ---------------------------------------------------------------------------
// Prep: img (fp32 planar re/im) -> B_pre (bf16, per-channel 64KB image in the
// exact LDS layout). Logical B[x][col], col = 2y+s (s=0:re, 1:im). Address:
// (256*col + 64*t4 + 16*q) ^ (16*(col&7)), x = 32*t4 + 8*q + j, +2*j.
// (mapping verified rounds 4-6)
// ---------------------------------------------------------------------------
__global__ __launch_bounds__(256) void prep_kernel(
    const float* __restrict__ img_real,
    const float* __restrict__ img_imag,
    unsigned short* __restrict__ B_pre)
{
    int tid = blockIdx.x * 256 + threadIdx.x;   // 32768 threads total
    int y  = tid & 127;
    int xc = (tid >> 7) & 15;                   // which 8-x chunk
    int s  = (tid >> 11) & 1;
    int c  = tid >> 12;
    int t4 = xc >> 2, q = xc & 3;
    int x0 = 32 * t4 + 8 * q;
    const float* src = (s ? img_imag : img_real) + c * (DNX * DNY) + y;
    float f[8];
    #pragma unroll
    for (int j = 0; j < 8; ++j) f[j] = src[(x0 + j) * DNY];
    int col  = 2 * y + s;
    int dest = (256 * col + 64 * t4 + 16 * q) ^ (16 * (col & 7));
    uint4 val;
    val.x = pkbf(f[0], f[1]);
    val.y = pkbf(f[2], f[3]);
    val.z = pkbf(f[4], f[5]);
    val.w = pkbf(f[6], f[7]);
    *(uint4*)((char*)B_pre + (size_t)c * 65536 + dest) = val;
}

// ---------------------------------------------------------------------------
// Main: block = 4 waves, each wave owns 32 k (2 k-groups of 16).
// Grid (128 kblocks, 4 chan-groups of 2 channels).
// Stage 1 (MFMA 16x16x32): acc1 += cos_frag*B, acc2 += sin_frag*B; one B
//   fragment read feeds 4 MFMAs.
// Stage 2 (lane-local, shuffle-free): F = sum acc1*cb - acc2*sb,
//   G = sum acc1*sb + acc2*cb with (cb,sb) advanced by incremental rotation;
//   kre-part = even-col ? F : -G, kim-part = even-col ? G : F;
//   16-lane DPP reduction at the end.
// ---------------------------------------------------------------------------
__global__ __launch_bounds__(256, 2) void nudft_mfma_kernel(
    const float* __restrict__ trj,
    const unsigned short* __restrict__ B_pre,
    float* __restrict__ out)
{
    __shared__ __align__(16) unsigned short Bl[32768];   // 64 KB single buffer

    const int t    = threadIdx.x;
    const int w    = t >> 6;          // wave 0..3
    const int lane = t & 63;
    const int m    = lane & 15;       // MFMA row (A) / col (C) index
    const int quad = (lane >> 4) & 3;
    const int spar = m & 1;           // col parity: 0 = re-col, 1 = im-col
    const int kb   = blockIdx.x;      // 0..127
    const int cg   = blockIdx.y;      // 0..3 -> channels 2cg, 2cg+1
    const int k0w  = kb * 128 + w * 32;

    // ---- A fragments (px) via incremental rotation + packed bf16 cvt:
    // A[m][x = 32*t4 + 8*quad + j]; theta(x) = d1*(x-64) pi-units, d1 = -trjx/64
    bf16x8 pxr[2][4], pxi[2][4];
    #pragma unroll
    for (int kg = 0; kg < 2; ++kg) {
        const float trjx = trj[2 * (k0w + kg * 16 + m) + 0];
        const float d1 = -trjx * (1.0f / 64.0f);
        float s1, c1;  sincospif(d1, &s1, &c1);            // rot per +1 x
        float s32, c32; sincospif(d1 * 32.0f, &s32, &c32); // rot per +32 x (t4 step)
        float ps, pc;  sincospif(d1 * (float)(8 * quad - 64), &ps, &pc);
        #pragma unroll
        for (int t4 = 0; t4 < 4; ++t4) {
            float qc = pc, qs = ps;
            float fc[8], fs[8];
            #pragma unroll
            for (int j = 0; j < 8; ++j) {
                fc[j] = qc; fs[j] = qs;
                if (j < 7) {
                    float tq = qc * c1 - qs * s1;
                    qs = fmaf(qc, s1, qs * c1);
                    qc = tq;
                }
            }
            uint32_t* pr = (uint32_t*)&pxr[kg][t4];
            uint32_t* pi = (uint32_t*)&pxi[kg][t4];
            #pragma unroll
            for (int p = 0; p < 4; ++p) {
                pr[p] = pkbf(fc[2 * p], fc[2 * p + 1]);
                pi[p] = pkbf(fs[2 * p], fs[2 * p + 1]);
            }
            if (t4 < 3) {
                float tp = pc * c32 - ps * s32;
                ps = fmaf(pc, s32, ps * c32);
                pc = tp;
            }
        }
    }

    // ---- stage-2 rotor init. Lane element idx=(kg,r): k = k0w+kg*16+quad*4+r,
    // y = ct*8 + ybase, ybase = m>>1. (cb,sb) = cos/sin(pi * -ty*(y-64)/64);
    // per-ct step rotor (dr,di) = cos/sin(pi * -ty/8). Parity-independent.
    const int ybase = m >> 1;
    float cb0[8], sb0[8], dr[8], di[8];
    #pragma unroll
    for (int kg = 0; kg < 2; ++kg) {
        #pragma unroll
        for (int r = 0; r < 4; ++r) {
            int idx = kg * 4 + r;
            float ty = trj[2 * (k0w + kg * 16 + quad * 4 + r) + 1];
            float sb, cbv; sincospif(-ty * (float)(ybase - 64) * (1.0f / 64.0f), &sb, &cbv);
            cb0[idx] = cbv; sb0[idx] = sb;
            float sd, cd; sincospif(-ty * 0.125f, &sd, &cd);
            dr[idx] = cd; di[idx] = sd;
        }
    }

    const int A0 = 256 * m + 16 * quad;
    const int Mx = 16 * (m & 7);             // XOR swizzle mask (col&7 == m&7)

    #pragma unroll 1
    for (int cc = 0; cc < 2; ++cc) {
        const int c = cg * 2 + cc;

        __syncthreads();   // previous channel fully consumed
        // stage channel c: wave w DMA-copies its 16 KB slice
        {
            const char* gbase = (const char*)B_pre + ((size_t)c << 16) + (w << 14) + (lane << 4);
            char* lbase = (char*)&Bl[0] + (w << 14);
            #pragma unroll
            for (int i = 0; i < 16; ++i) {
                __builtin_amdgcn_global_load_lds(
                    (gp_t)(const void*)(gbase + (i << 10)),
                    (lp_t)(void*)(lbase + (i << 10)),
                    16, 0, 0);
            }
        }
        __syncthreads();   // DMA drained (vmcnt(0) before barrier)

        float F[8], G[8], cb[8], sb[8];
        #pragma unroll
        for (int idx = 0; idx < 8; ++idx) {
            F[idx] = 0.f; G[idx] = 0.f;
            cb[idx] = cb0[idx]; sb[idx] = sb0[idx];
        }

        #pragma unroll 2
        for (int ct = 0; ct < 16; ++ct) {
            f32x4 acc1[2], acc2[2];
            #pragma unroll
            for (int kg = 0; kg < 2; ++kg) {
                acc1[kg] = (f32x4){0.f, 0.f, 0.f, 0.f};
                acc2[kg] = (f32x4){0.f, 0.f, 0.f, 0.f};
            }
            const int Act = A0 + 4096 * ct;
            #pragma unroll
            for (int t4 = 0; t4 < 4; ++t4) {
                int addr = (Act + 64 * t4) ^ Mx;
                bf16x8 bfrag = *(const bf16x8*)((const char*)&Bl[0] + addr);
                acc1[0] = __builtin_amdgcn_mfma_f32_16x16x32_bf16(pxr[0][t4], bfrag, acc1[0], 0, 0, 0);
                acc2[0] = __builtin_amdgcn_mfma_f32_16x16x32_bf16(pxi[0][t4], bfrag, acc2[0], 0, 0, 0);
                acc1[1] = __builtin_amdgcn_mfma_f32_16x16x32_bf16(pxr[1][t4], bfrag, acc1[1], 0, 0, 0);
                acc2[1] = __builtin_amdgcn_mfma_f32_16x16x32_bf16(pxi[1][t4], bfrag, acc2[1], 0, 0, 0);
            }
            #pragma unroll
            for (int kg = 0; kg < 2; ++kg) {
                #pragma unroll
                for (int r = 0; r < 4; ++r) {
                    const int idx = kg * 4 + r;
                    float a1 = acc1[kg][r], a2 = acc2[kg][r];
                    F[idx] = fmaf(a1, cb[idx], F[idx]);
                    F[idx] = fmaf(-a2, sb[idx], F[idx]);
                    G[idx] = fmaf(a1, sb[idx], G[idx]);
                    G[idx] = fmaf(a2, cb[idx], G[idx]);
                    // advance rotor
                    float tz = cb[idx] * dr[idx] - sb[idx] * di[idx];
                    sb[idx]  = fmaf(cb[idx], di[idx], sb[idx] * dr[idx]);
                    cb[idx]  = tz;
                }
            }
        }

        // per-lane parity assignment, then 16-lane DPP reduction (VALU only)
        #pragma unroll
        for (int idx = 0; idx < 8; ++idx) {
            float kre_p = spar ? -G[idx] : F[idx];
            float kim_p = spar ?  F[idx] : G[idx];
            float kre_s = dpp_sum16(kre_p);
            float kim_s = dpp_sum16(kim_p);
            if (m == 0) {
                int kg = idx >> 2, r = idx & 3;
                int k = k0w + kg * 16 + quad * 4 + r;
                out[(size_t)c * KPTS + k]                      = kre_s;
                out[(size_t)NCH * KPTS + (size_t)c * KPTS + k] = kim_s;
            }
        }
    }
}

extern "C" void kernel_launch(void* const* d_in, const int* in_sizes, int n_in,
                              void* d_out, int out_size, void* d_ws, size_t ws_size,
                              hipStream_t stream)
{
    const float* img_real = (const float*)d_in[0];  // (8,128,128) fp32
    const float* img_imag = (const float*)d_in[1];  // (8,128,128) fp32
    const float* trj      = (const float*)d_in[2];  // (16384,2) fp32
    float* out = (float*)d_out;                      // planar: re block then im block
    unsigned short* B_pre = (unsigned short*)d_ws;   // 512 KB bf16 pre-swizzled img

    prep_kernel<<<128, 256, 0, stream>>>(img_real, img_imag, B_pre);
    nudft_mfma_kernel<<<dim3(128, 4), 256, 0, stream>>>(trj, B_pre, out);
}